// Round 4
// baseline (329.062 us; speedup 1.0000x reference)
//
#include <hip/hip_runtime.h>

#define NROWS 8192   // N == M == 8192
#define DDIM  512
#define OUTN  8192

typedef int   i32x4 __attribute__((ext_vector_type(4)));
typedef int   i32x8 __attribute__((ext_vector_type(8)));
typedef float f32x4 __attribute__((ext_vector_type(4)));

__device__ __forceinline__ void gload_lds16(const void* g, void* l) {
    __builtin_amdgcn_global_load_lds(
        (const __attribute__((address_space(1))) void*)g,
        (__attribute__((address_space(3))) void*)l, 16, 0, 0);
}

// ---------------------------------------------------------------------------
// Prepass: fp32 -> fp8 e4m3 (OCP) + fp32 row sq-norms. One wave per row.
// ---------------------------------------------------------------------------
__global__ void __launch_bounds__(256)
rbf_prep(const float* __restrict__ x, const float* __restrict__ y,
         unsigned char* __restrict__ xb, unsigned char* __restrict__ yb,
         float* __restrict__ x2, float* __restrict__ y2) {
    int wave = (blockIdx.x * blockDim.x + threadIdx.x) >> 6;  // 0..16383
    int lane = threadIdx.x & 63;

    const float* src;
    unsigned char* dst;
    float* nrm;
    int row;
    if (wave < NROWS) { src = x; dst = xb; nrm = x2; row = wave; }
    else              { src = y; dst = yb; nrm = y2; row = wave - NROWS; }

    const float* p = src + (size_t)row * DDIM + lane * 8;
    float4 v0 = *(const float4*)(p);
    float4 v1 = *(const float4*)(p + 4);

    float s = v0.x * v0.x + v0.y * v0.y + v0.z * v0.z + v0.w * v0.w
            + v1.x * v1.x + v1.y * v1.y + v1.z * v1.z + v1.w * v1.w;

    int lo = __builtin_amdgcn_cvt_pk_fp8_f32(v0.x, v0.y, 0, false);
    lo     = __builtin_amdgcn_cvt_pk_fp8_f32(v0.z, v0.w, lo, true);
    int hi = __builtin_amdgcn_cvt_pk_fp8_f32(v1.x, v1.y, 0, false);
    hi     = __builtin_amdgcn_cvt_pk_fp8_f32(v1.z, v1.w, hi, true);
    *(int2*)(dst + (size_t)row * DDIM + lane * 8) = make_int2(lo, hi);

#pragma unroll
    for (int off = 32; off > 0; off >>= 1) s += __shfl_down(s, off, 64);
    if (lane == 0) nrm[row] = s;
}

// ---------------------------------------------------------------------------
// Fused GEMM + RBF epilogue, MX-fp8 (scale = 1.0).
// K-loop: R2 structure (BK=128, 32 KB staging LDS, global_load_lds width=16,
// XOR chunk-swizzle on the GLOBAL side; LDS dest stays base+lane*16).
// Epilogue: expf in-register, then LDS-transpose (stride 132 f32, 2-way bank
// aliasing = free) and fully-coalesced nontemporal global_store_dwordx4
// (512 B contiguous per 32-lane half -> complete 128 B lines, safe for nt).
// ---------------------------------------------------------------------------
__global__ void __launch_bounds__(256)
rbf_gemm(const unsigned char* __restrict__ xb,
         const unsigned char* __restrict__ yb,
         const float* __restrict__ x2, const float* __restrict__ y2,
         const float* __restrict__ gamma, float* __restrict__ out) {
    // 34048 B: staging As(16K)+Bs(16K) in K-loop; epilogue reuses it as a
    // 64 x 132-stride f32 tile (33792 B).
    __shared__ __attribute__((aligned(16))) unsigned char smem[34048];
    unsigned char* As = smem;
    unsigned char* Bs = smem + 16384;
    float* T = (float*)smem;           // epilogue transpose tile [64][132]

    const int tid  = threadIdx.x;
    const int lane = tid & 63;
    const int w    = tid >> 6;        // wave 0..3
    const int wm   = w & 1;           // wave row (0..1)
    const int wn   = w >> 1;          // wave col (0..1)

    const int bm = blockIdx.x & 63;
    const int bn = blockIdx.x >> 6;
    const int row0 = bm * 128;
    const int col0 = bn * 128;

    f32x4 acc[4][4] = {};

    // staging: each issue stages 8 rows x 128 B; lane L -> row L>>3, chunk L&7
    const int srl = lane >> 3;               // row within 8-row group
    const int sgc = ((lane & 7) ^ srl) * 16; // swizzled GLOBAL byte chunk

    for (int k0 = 0; k0 < DDIM; k0 += 128) {
#pragma unroll
        for (int i = 0; i < 4; ++i) {
            int rg = w * 32 + i * 8;   // wave-uniform row group (8 rows)
            gload_lds16(xb + (size_t)(row0 + rg + srl) * DDIM + k0 + sgc,
                        As + rg * 128);
            gload_lds16(yb + (size_t)(col0 + rg + srl) * DDIM + k0 + sgc,
                        Bs + rg * 128);
        }
        __syncthreads();

        // fragment loads: LDS chunk = global chunk ^ (row & 7); row&7 == lane&7
        const int sw = lane & 7;
        const int g2 = (lane >> 4) * 2;
        i32x8 af[4], bfr[4];
#pragma unroll
        for (int mi = 0; mi < 4; ++mi) {
            const unsigned char* base = As + (wm * 64 + mi * 16 + (lane & 15)) * 128;
            i32x4 lo = *(const i32x4*)(base + ((g2    ) ^ sw) * 16);
            i32x4 hi = *(const i32x4*)(base + ((g2 + 1) ^ sw) * 16);
            af[mi] = __builtin_shufflevector(lo, hi, 0, 1, 2, 3, 4, 5, 6, 7);
        }
#pragma unroll
        for (int ni = 0; ni < 4; ++ni) {
            const unsigned char* base = Bs + (wn * 64 + ni * 16 + (lane & 15)) * 128;
            i32x4 lo = *(const i32x4*)(base + ((g2    ) ^ sw) * 16);
            i32x4 hi = *(const i32x4*)(base + ((g2 + 1) ^ sw) * 16);
            bfr[ni] = __builtin_shufflevector(lo, hi, 0, 1, 2, 3, 4, 5, 6, 7);
        }
#pragma unroll
        for (int mi = 0; mi < 4; ++mi)
#pragma unroll
            for (int ni = 0; ni < 4; ++ni)
                acc[mi][ni] = __builtin_amdgcn_mfma_scale_f32_16x16x128_f8f6f4(
                    af[mi], bfr[ni], acc[mi][ni],
                    0, 0,          // cbsz/blgp = fp8 e4m3
                    0, 0x7F,       // A scale = 1.0 (E8M0 127)
                    0, 0x7F);      // B scale = 1.0
        __syncthreads();
    }

    // ---- Epilogue ----
    // C/D layout (16x16): col = lane&15, row = (lane>>4)*4 + reg.
    // Two passes of 64 output rows. Pass p: waves with wm==p apply
    // exp(-g*(x2+y2-2*xy)) and write their 64x64 quadrant into T (row-major,
    // stride 132); then all 256 threads stream T out coalesced.
    const float g = gamma[0];
    const int q4 = (lane >> 4) * 4;
    const int cs = lane & 15;

#pragma unroll
    for (int p = 0; p < 2; ++p) {
        if (wm == p) {
#pragma unroll
            for (int mi = 0; mi < 4; ++mi) {
                const int lr0 = mi * 16 + q4;                 // local row base 0..63
                float xn[4];
#pragma unroll
                for (int r = 0; r < 4; ++r)
                    xn[r] = x2[row0 + p * 64 + lr0 + r];
#pragma unroll
                for (int ni = 0; ni < 4; ++ni) {
                    const int lc = wn * 64 + ni * 16 + cs;    // local col 0..127
                    const float yn = y2[col0 + lc];
#pragma unroll
                    for (int r = 0; r < 4; ++r) {
                        float s = xn[r] + yn - 2.0f * acc[mi][ni][r];
                        T[(lr0 + r) * 132 + lc] = __expf(-g * s);
                    }
                }
            }
        }
        __syncthreads();
        // coalesced streaming store: 64 rows x 128 cols, float4 per thread x8
#pragma unroll
        for (int i = 0; i < 8; ++i) {
            int li = i * 256 + tid;          // 0..2047 float4-slots
            int lr = li >> 5;                // row 0..63
            int c4 = (li & 31) * 4;          // col 0..124
            f32x4 v = *(const f32x4*)(T + lr * 132 + c4);
            float* op = out + (size_t)(row0 + p * 64 + lr) * OUTN + col0 + c4;
            __builtin_nontemporal_store(v, (f32x4*)op);
        }
        __syncthreads();
    }
}

extern "C" void kernel_launch(void* const* d_in, const int* in_sizes, int n_in,
                              void* d_out, int out_size, void* d_ws, size_t ws_size,
                              hipStream_t stream) {
    const float* x     = (const float*)d_in[0];
    const float* y     = (const float*)d_in[1];
    const float* gamma = (const float*)d_in[2];
    float* out = (float*)d_out;

    // workspace: xb (4 MB) | yb (4 MB) | x2 (32 KB) | y2 (32 KB)
    char* ws = (char*)d_ws;
    unsigned char* xb = (unsigned char*)ws;
    unsigned char* yb = (unsigned char*)(ws + (size_t)NROWS * DDIM);
    float* x2 = (float*)(ws + (size_t)NROWS * DDIM * 2);
    float* y2 = (float*)(ws + (size_t)NROWS * DDIM * 2 + NROWS * 4);

    rbf_prep<<<4096, 256, 0, stream>>>(x, y, xb, yb, x2, y2);
    rbf_gemm<<<4096, 256, 0, stream>>>(xb, yb, x2, y2, gamma, out);
}

// Round 5
// 311.474 us; speedup vs baseline: 1.0565x; 1.0565x over previous
//
#include <hip/hip_runtime.h>

#define NROWS 8192   // N == M == 8192
#define DDIM  512
#define OUTN  8192

typedef int   i32x4 __attribute__((ext_vector_type(4)));
typedef int   i32x8 __attribute__((ext_vector_type(8)));
typedef float f32x4 __attribute__((ext_vector_type(4)));

// ---------------------------------------------------------------------------
// Prepass: fp32 -> fp8 e4m3 (OCP) + fp32 row sq-norms, emitting the fp8 data
// DIRECTLY IN MFMA FRAGMENT LAYOUT so the GEMM needs no LDS and no barriers.
//
// Fragment layout for mfma_scale_f32_16x16x128_f8f6f4 (A and B identical):
// lane l holds row (l&15), k-bytes (l>>4)*32 .. +32 of a 128-k window.
// Storage: off(group, h, l, b) = group*8192 + h*2048 + l*32 + b
//   where group = row>>4 (16-row group), h = k-window (0..3), b = 0..31.
// A wave's 64 lanes then read 2 KB contiguous per (group,h): 2x dwordx4/lane.
//
// One wave per row. Lane covers k = lane*8..+7:
//   h = lane>>4, kq = (lane>>2)&3, kb = (lane&3)*8
//   off = (row>>4)*8192 + h*2048 + kq*512 + (row&15)*32 + kb
// (matches the layout above since l*32 = (l>>4)*512 + (l&15)*32 with the
// fragment-lane's l>>4 = kq and l&15 = row&15.)
// ---------------------------------------------------------------------------
__global__ void __launch_bounds__(256)
rbf_prep(const float* __restrict__ x, const float* __restrict__ y,
         unsigned char* __restrict__ xs, unsigned char* __restrict__ ys,
         float* __restrict__ x2, float* __restrict__ y2) {
    int wave = (blockIdx.x * blockDim.x + threadIdx.x) >> 6;  // 0..16383
    int lane = threadIdx.x & 63;

    const float* src;
    unsigned char* dst;
    float* nrm;
    int row;
    if (wave < NROWS) { src = x; dst = xs; nrm = x2; row = wave; }
    else              { src = y; dst = ys; nrm = y2; row = wave - NROWS; }

    const float* p = src + (size_t)row * DDIM + lane * 8;
    float4 v0 = *(const float4*)(p);
    float4 v1 = *(const float4*)(p + 4);

    float s = v0.x * v0.x + v0.y * v0.y + v0.z * v0.z + v0.w * v0.w
            + v1.x * v1.x + v1.y * v1.y + v1.z * v1.z + v1.w * v1.w;

    int lo = __builtin_amdgcn_cvt_pk_fp8_f32(v0.x, v0.y, 0, false);
    lo     = __builtin_amdgcn_cvt_pk_fp8_f32(v0.z, v0.w, lo, true);
    int hi = __builtin_amdgcn_cvt_pk_fp8_f32(v1.x, v1.y, 0, false);
    hi     = __builtin_amdgcn_cvt_pk_fp8_f32(v1.z, v1.w, hi, true);

    int h  = lane >> 4;
    int kq = (lane >> 2) & 3;
    int kb = (lane & 3) * 8;
    size_t off = (size_t)(row >> 4) * 8192 + h * 2048 + kq * 512
               + (row & 15) * 32 + kb;
    *(int2*)(dst + off) = make_int2(lo, hi);

#pragma unroll
    for (int off2 = 32; off2 > 0; off2 >>= 1) s += __shfl_down(s, off2, 64);
    if (lane == 0) nrm[row] = s;
}

// ---------------------------------------------------------------------------
// Fused GEMM + RBF epilogue, MX-fp8 (scale = 1.0), BARRIER-FREE.
// Inputs are pre-swizzled into fragment layout, so each wave loads its MFMA
// fragments straight from global (L2-resident: per-XCD working set ~576 KB
// during a bn-sweep) with global_load_dwordx4 — no LDS, no __syncthreads.
// 128x128 block tile, 4 waves (2x2), wave = 4x4 of 16x16x128 MFMAs over
// 4 k-windows. Occupancy is VGPR-bound (~2 waves/SIMD); waves are fully
// independent so there is no barrier drain to stall them.
// ---------------------------------------------------------------------------
__global__ void __launch_bounds__(256)
rbf_gemm(const unsigned char* __restrict__ xs,
         const unsigned char* __restrict__ ys,
         const float* __restrict__ x2, const float* __restrict__ y2,
         const float* __restrict__ gamma, float* __restrict__ out) {
    const int tid  = threadIdx.x;
    const int lane = tid & 63;
    const int w    = tid >> 6;        // wave 0..3
    const int wm   = w & 1;           // wave row (0..1)
    const int wn   = w >> 1;          // wave col (0..1)

    const int bm = blockIdx.x & 63;   // fast-varying -> consecutive blocks
    const int bn = blockIdx.x >> 6;   //   share the B tile (L2 locality)
    const int row0 = bm * 128;
    const int col0 = bn * 128;

    f32x4 acc[4][4] = {};

    // fragment base: group (bm*8 + wm*4 + mi), window h, lane*32
    const unsigned char* abase = xs + (size_t)(bm * 8 + wm * 4) * 8192 + lane * 32;
    const unsigned char* bbase = ys + (size_t)(bn * 8 + wn * 4) * 8192 + lane * 32;

#pragma unroll 2
    for (int h = 0; h < 4; ++h) {
        i32x8 af[4], bfr[4];
#pragma unroll
        for (int mi = 0; mi < 4; ++mi) {
            const unsigned char* p = abase + mi * 8192 + h * 2048;
            i32x4 lo = *(const i32x4*)(p);
            i32x4 hi = *(const i32x4*)(p + 16);
            af[mi] = __builtin_shufflevector(lo, hi, 0, 1, 2, 3, 4, 5, 6, 7);
        }
#pragma unroll
        for (int ni = 0; ni < 4; ++ni) {
            const unsigned char* p = bbase + ni * 8192 + h * 2048;
            i32x4 lo = *(const i32x4*)(p);
            i32x4 hi = *(const i32x4*)(p + 16);
            bfr[ni] = __builtin_shufflevector(lo, hi, 0, 1, 2, 3, 4, 5, 6, 7);
        }
#pragma unroll
        for (int mi = 0; mi < 4; ++mi)
#pragma unroll
            for (int ni = 0; ni < 4; ++ni)
                acc[mi][ni] = __builtin_amdgcn_mfma_scale_f32_16x16x128_f8f6f4(
                    af[mi], bfr[ni], acc[mi][ni],
                    0, 0,          // cbsz/blgp = fp8 e4m3
                    0, 0x7F,       // A scale = 1.0 (E8M0 127)
                    0, 0x7F);      // B scale = 1.0
    }

    // Epilogue (R2 form — best known): out[r][c] = exp(-g*(x2[r]+y2[c]-2*xy))
    // C/D layout (16x16): col = lane&15, row = (lane>>4)*4 + reg.
    // Plain scalar stores; L2 write-back merges the 64 B segments into lines.
    const float g = gamma[0];
#pragma unroll
    for (int mi = 0; mi < 4; ++mi) {
        const int rbase = row0 + wm * 64 + mi * 16 + (lane >> 4) * 4;
        float xn[4];
#pragma unroll
        for (int r = 0; r < 4; ++r) xn[r] = x2[rbase + r];
#pragma unroll
        for (int ni = 0; ni < 4; ++ni) {
            const int col = col0 + wn * 64 + ni * 16 + (lane & 15);
            const float yn = y2[col];
            float* op = out + (size_t)rbase * OUTN + col;
#pragma unroll
            for (int r = 0; r < 4; ++r) {
                float s = xn[r] + yn - 2.0f * acc[mi][ni][r];
                op[(size_t)r * OUTN] = __expf(-g * s);
            }
        }
    }
}

extern "C" void kernel_launch(void* const* d_in, const int* in_sizes, int n_in,
                              void* d_out, int out_size, void* d_ws, size_t ws_size,
                              hipStream_t stream) {
    const float* x     = (const float*)d_in[0];
    const float* y     = (const float*)d_in[1];
    const float* gamma = (const float*)d_in[2];
    float* out = (float*)d_out;

    // workspace: xs (4 MB, swizzled fp8) | ys (4 MB) | x2 (32 KB) | y2 (32 KB)
    char* ws = (char*)d_ws;
    unsigned char* xs = (unsigned char*)ws;
    unsigned char* ys = (unsigned char*)(ws + (size_t)NROWS * DDIM);
    float* x2 = (float*)(ws + (size_t)NROWS * DDIM * 2);
    float* y2 = (float*)(ws + (size_t)NROWS * DDIM * 2 + NROWS * 4);

    rbf_prep<<<4096, 256, 0, stream>>>(x, y, xs, ys, x2, y2);
    rbf_gemm<<<4096, 256, 0, stream>>>(xs, ys, x2, y2, gamma, out);
}